// Round 2
// baseline (168.733 us; speedup 1.0000x reference)
//
#include <hip/hip_runtime.h>

// Sizes (fixed by the problem)
#define B_ 8192
#define T_ 256
#define I_ 28
#define H_ 10

// d_out layout: [B*T*H] output, then [2*B*H] h_final
#define OUT_MAIN (B_ * T_ * H_)   // 20971520
#define BH (B_ * H_)              // 81920

__device__ __forceinline__ float fast_tanh(float x) {
    // tanh(x) = 1 - 2/(exp(2x)+1); exp(2x) = exp2(x * 2*log2(e))
    float e = __builtin_amdgcn_exp2f(x * 2.885390081777927f);
    return __builtin_fmaf(-2.0f, __builtin_amdgcn_rcpf(e + 1.0f), 1.0f);
}

// ---------------- K1: xw0[b][t][u] = sum_i x[b][t][i] * Wih0[u][i] + (bih0[u]+bhh0[u])
// 2 rows (b,t) per thread. Weights staged in LDS (broadcast reads).
__global__ __launch_bounds__(256) void rnn_k1(
        const float* __restrict__ x, const float* __restrict__ Wih0,
        const float* __restrict__ bih0, const float* __restrict__ bhh0,
        float* __restrict__ xw0) {
    __shared__ float Wl[H_ * I_];
    __shared__ float bl[H_];
    int tid = threadIdx.x;
    // H_*I_ = 280 > 256: MUST loop (round-1 bug: single guarded store left
    // Wl[256..279] uninitialized -> unit 9 garbage -> absmax 0.8)
    for (int i = tid; i < H_ * I_; i += 256) Wl[i] = Wih0[i];
    if (tid < H_) bl[tid] = bih0[tid] + bhh0[tid];
    __syncthreads();

    long row0 = ((long)blockIdx.x * 256 + tid) * 2;
    const float* xr = x + row0 * I_;
    float xa[I_], xb[I_];
#pragma unroll
    for (int i = 0; i < 7; i++) {
        float4 va = ((const float4*)xr)[i];
        float4 vb = ((const float4*)(xr + I_))[i];
        xa[4*i+0] = va.x; xa[4*i+1] = va.y; xa[4*i+2] = va.z; xa[4*i+3] = va.w;
        xb[4*i+0] = vb.x; xb[4*i+1] = vb.y; xb[4*i+2] = vb.z; xb[4*i+3] = vb.w;
    }
    float oa[H_], ob[H_];
#pragma unroll
    for (int u = 0; u < H_; u++) {
        float s0 = bl[u], s1 = bl[u];
#pragma unroll
        for (int i = 0; i < I_; i++) {
            float w = Wl[u * I_ + i];
            s0 = __builtin_fmaf(xa[i], w, s0);
            s1 = __builtin_fmaf(xb[i], w, s1);
        }
        oa[u] = s0; ob[u] = s1;
    }
    float* o = xw0 + row0 * H_;
#pragma unroll
    for (int i = 0; i < 5; i++) {
        ((float2*)o)[i]        = make_float2(oa[2*i], oa[2*i+1]);
        ((float2*)(o + H_))[i] = make_float2(ob[2*i], ob[2*i+1]);
    }
}

// ---------------- K2: recurrent pass. 8 lanes per batch; lanes 0-4 own units (2j, 2j+1).
// h vectors replicated across the 8-lane group via ds_swizzle broadcasts
// (BitMode src = (i & 0x18) | s, s=0..4 -> imm (s<<5)|0x18).
// xw0 lives in d_out's main region and is overwritten in place by h1 (reads lead writes by 4 steps).

#define SWZ(v, imm) __int_as_float(__builtin_amdgcn_ds_swizzle(__float_as_int(v), (imm)))

__global__ __launch_bounds__(256) void rnn_k2(
        float* __restrict__ buf,            // d_out: xw0 in, output out
        const float* __restrict__ h0in,     // [2][B][H]
        const float* __restrict__ Whh0, const float* __restrict__ Wih1,
        const float* __restrict__ Whh1,
        const float* __restrict__ bih1, const float* __restrict__ bhh1,
        float* __restrict__ hfin) {         // d_out + OUT_MAIN
    int id = blockIdx.x * 256 + threadIdx.x;
    int b = id >> 3;
    int j = id & 7;
    bool act = (j < 5);
    int u0 = act ? 2 * j : 0;
    int u1 = act ? 2 * j + 1 : 0;

    float wh0a[H_], wh0b[H_], wi1a[H_], wi1b[H_], wh1a[H_], wh1b[H_];
#pragma unroll
    for (int k = 0; k < H_; k++) {
        wh0a[k] = Whh0[u0 * H_ + k]; wh0b[k] = Whh0[u1 * H_ + k];
        wi1a[k] = Wih1[u0 * H_ + k]; wi1b[k] = Wih1[u1 * H_ + k];
        wh1a[k] = Whh1[u0 * H_ + k]; wh1b[k] = Whh1[u1 * H_ + k];
    }
    float bb0 = bih1[u0] + bhh1[u0];
    float bb1 = bih1[u1] + bhh1[u1];

    float h0[H_], h1[H_];
#pragma unroll
    for (int k = 0; k < H_; k++) {
        h0[k] = h0in[b * H_ + k];
        h1[k] = h0in[BH + b * H_ + k];
    }

    float* base = buf + (long)b * (T_ * H_);
    float2 xbuf[4];
#pragma unroll
    for (int q = 0; q < 4; q++)
        xbuf[q] = act ? *(const float2*)(base + q * H_ + u0) : make_float2(0.f, 0.f);

    for (int t = 0; t < T_; t += 4) {
#pragma unroll
        for (int q = 0; q < 4; q++) {
            int tc = t + q;
            float a0 = xbuf[q].x, a1 = xbuf[q].y;
            // prefetch 4 steps ahead
            if (tc + 4 < T_ && act)
                xbuf[q] = *(const float2*)(base + (tc + 4) * H_ + u0);
            // layer 0: a = xw0 + h0 . Whh0_row
#pragma unroll
            for (int k = 0; k < H_; k++) {
                a0 = __builtin_fmaf(h0[k], wh0a[k], a0);
                a1 = __builtin_fmaf(h0[k], wh0b[k], a1);
            }
            float n0 = fast_tanh(a0), n1 = fast_tanh(a1);
            // broadcast h0_new to the whole 8-lane group (src lanes 0..4)
            h0[0] = SWZ(n0, 0x18); h0[1] = SWZ(n1, 0x18);
            h0[2] = SWZ(n0, 0x38); h0[3] = SWZ(n1, 0x38);
            h0[4] = SWZ(n0, 0x58); h0[5] = SWZ(n1, 0x58);
            h0[6] = SWZ(n0, 0x78); h0[7] = SWZ(n1, 0x78);
            h0[8] = SWZ(n0, 0x98); h0[9] = SWZ(n1, 0x98);
            // layer 1
            float c0 = bb0, c1 = bb1;
#pragma unroll
            for (int k = 0; k < H_; k++) {
                c0 = __builtin_fmaf(h0[k], wi1a[k], c0);
                c1 = __builtin_fmaf(h0[k], wi1b[k], c1);
                c0 = __builtin_fmaf(h1[k], wh1a[k], c0);
                c1 = __builtin_fmaf(h1[k], wh1b[k], c1);
            }
            float m0 = fast_tanh(c0), m1 = fast_tanh(c1);
            // store output (own units), overwrites consumed xw0 slot
            if (act)
                *(float2*)(base + tc * H_ + u0) = make_float2(m0, m1);
            // broadcast h1_new
            h1[0] = SWZ(m0, 0x18); h1[1] = SWZ(m1, 0x18);
            h1[2] = SWZ(m0, 0x38); h1[3] = SWZ(m1, 0x38);
            h1[4] = SWZ(m0, 0x58); h1[5] = SWZ(m1, 0x58);
            h1[6] = SWZ(m0, 0x78); h1[7] = SWZ(m1, 0x78);
            h1[8] = SWZ(m0, 0x98); h1[9] = SWZ(m1, 0x98);
        }
    }
    if (act) {
        *(float2*)(hfin + b * H_ + u0)      = make_float2(h0[u0], h0[u1]);
        *(float2*)(hfin + BH + b * H_ + u0) = make_float2(h1[u0], h1[u1]);
    }
}

extern "C" void kernel_launch(void* const* d_in, const int* in_sizes, int n_in,
                              void* d_out, int out_size, void* d_ws, size_t ws_size,
                              hipStream_t stream) {
    const float* x     = (const float*)d_in[0];
    const float* h0in  = (const float*)d_in[1];
    const float* Wih0  = (const float*)d_in[2];
    const float* Whh0  = (const float*)d_in[3];
    const float* bih0  = (const float*)d_in[4];
    const float* bhh0  = (const float*)d_in[5];
    const float* Wih1  = (const float*)d_in[6];
    const float* Whh1  = (const float*)d_in[7];
    const float* bih1  = (const float*)d_in[8];
    const float* bhh1  = (const float*)d_in[9];
    float* out = (float*)d_out;

    // K1: xw0 into d_out main region. 2M rows, 2 rows/thread, 256 thr/blk -> 4096 blocks
    rnn_k1<<<dim3((B_ * T_) / 512), dim3(256), 0, stream>>>(x, Wih0, bih0, bhh0, out);
    // K2: 8 lanes/batch -> 65536 threads -> 256 blocks
    rnn_k2<<<dim3(256), dim3(256), 0, stream>>>(out, h0in, Whh0, Wih1, Whh1,
                                                bih1, bhh1, out + OUT_MAIN);
}